// Round 2
// baseline (605.552 us; speedup 1.0000x reference)
//
#include <hip/hip_runtime.h>
#include <math.h>

#define NODE_IN 64
#define NODE_OUT 96
#define EDGE_IN 16
#define EDGE_OUT 64
#define ACC_W 80          // NODE_IN + EDGE_IN
#define NB 500            // graphs
#define FPD 2048
#define FPE 128
#define XDIM 288          // 160 + 128
#define BN_EPS 1e-5f

static __device__ __forceinline__ float rl_f(float v, int l) {
    return __int_as_float(__builtin_amdgcn_readlane(__float_as_int(v), l));
}

// ---------------- Kernel 1: per-edge scatter of raw features into per-block
// LDS accumulators [500][80] (+ per-graph edge count), flushed to partials.
// Pipelined: 16-deep node-row loads, 8-deep edge loads, 2-deep batch prefetch.
__global__ __launch_bounds__(1024) void edge_scatter(
    const float* __restrict__ node_feats, const float* __restrict__ edge_feats,
    const int* __restrict__ src, const int* __restrict__ dst,
    const int* __restrict__ gids,
    float* __restrict__ pf, int* __restrict__ pi, int E)
{
    __shared__ float acc[NB * ACC_W];   // 160000 B
    __shared__ int   scnt[NB];          // 2000 B
    const int t = threadIdx.x;
    for (int i = t; i < NB * ACC_W; i += 1024) acc[i] = 0.f;
    for (int i = t; i < NB; i += 1024) scnt[i] = 0;
    __syncthreads();

    const int lane = t & 63;
    const int wid  = blockIdx.x * 16 + (t >> 6);
    const int nw   = gridDim.x * 16;
    const int nbatch = (E + 63) >> 6;
    const int q  = lane >> 4;      // edge-part: 4 edges x 16 feats per wave-op
    const int jj = lane & 15;

    // prologue: prefetch first batch's (src, graph) for this wave
    int gp = -1, sp = 0;
    {
        const int e = (wid << 6) + lane;
        if (wid < nbatch && e < E) { sp = src[e]; gp = gids[dst[e]]; }
    }

    for (int b = wid; b < nbatch; b += nw) {
        const int e0 = b << 6;
        const int g = gp, s = sp;

        // prefetch next batch (two dependent loads hide under this batch's work)
        const int bn = b + nw;
        int gn = -1, sn = 0;
        if (bn < nbatch) {
            const int en = (bn << 6) + lane;
            if (en < E) { sn = src[en]; gn = gids[dst[en]]; }
        }

        if (g >= 0) atomicAdd(&scnt[g], 1);

        // node part: lane j holds feature j; 16 row-loads in flight, then 16 atomics.
        #pragma unroll
        for (int i0 = 0; i0 < 64; i0 += 16) {
            float v[16];
            int   gg[16];
            #pragma unroll
            for (int u = 0; u < 16; ++u) {
                const int si = __builtin_amdgcn_readlane(s, i0 + u);
                gg[u] = __builtin_amdgcn_readlane(g, i0 + u);
                v[u] = node_feats[(size_t)si * NODE_IN + lane];
            }
            #pragma unroll
            for (int u = 0; u < 16; ++u)
                if (gg[u] >= 0) atomicAdd(&acc[gg[u] * ACC_W + lane], v[u]);
        }

        // edge part: 4 edges x 16 features per wave-op, 8-deep pipelined.
        // g broadcast via readlane+select (VALU) to keep the LDS pipe free.
        #pragma unroll
        for (int k0 = 0; k0 < 16; k0 += 8) {
            float w[8];
            int   gq[8];
            #pragma unroll
            for (int u = 0; u < 8; ++u) {
                const int k = k0 + u;
                const int r0 = __builtin_amdgcn_readlane(g, k * 4 + 0);
                const int r1 = __builtin_amdgcn_readlane(g, k * 4 + 1);
                const int r2 = __builtin_amdgcn_readlane(g, k * 4 + 2);
                const int r3 = __builtin_amdgcn_readlane(g, k * 4 + 3);
                const int gg = (q == 0) ? r0 : (q == 1) ? r1 : (q == 2) ? r2 : r3;
                gq[u] = gg;
                w[u] = (gg >= 0) ? edge_feats[(size_t)(e0 + k * 4 + q) * EDGE_IN + jj] : 0.f;
            }
            #pragma unroll
            for (int u = 0; u < 8; ++u)
                if (gq[u] >= 0) atomicAdd(&acc[gq[u] * ACC_W + NODE_IN + jj], w[u]);
        }

        gp = gn; sp = sn;
    }
    __syncthreads();
    for (int i = t; i < NB * ACC_W; i += 1024)
        pf[(size_t)blockIdx.x * (NB * ACC_W) + i] = acc[i];
    for (int i = t; i < NB; i += 1024)
        pi[(size_t)blockIdx.x * NB + i] = scnt[i];
}

// ---------------- Kernel 2: reduce partials, tiny GEMMs, softmax -> x[:, :160]
__global__ __launch_bounds__(256) void mol_kernel(
    const float* __restrict__ pf, const int* __restrict__ pi, int nblk,
    const float* __restrict__ Wm, const float* __restrict__ bm,
    const float* __restrict__ We, const float* __restrict__ be,
    float* __restrict__ xbuf)
{
    const int g = blockIdx.x;
    const int t = threadIdx.x;
    __shared__ float acc[ACC_W];
    __shared__ float red[256];
    __shared__ int   ired[256];
    __shared__ float molrow[160];

    float s = 0.f;
    if (t < 240) {
        const int c = t % 80, seg = t / 80;
        for (int b = seg; b < nblk; b += 3)
            s += pf[(size_t)b * (NB * ACC_W) + g * ACC_W + c];
    }
    red[t] = s;
    int ci = 0;
    for (int b = t; b < nblk; b += 256) ci += pi[(size_t)b * NB + g];
    ired[t] = ci;
    __syncthreads();
    if (t < 80) acc[t] = red[t] + red[t + 80] + red[t + 160];
    for (int st = 128; st > 0; st >>= 1) {
        if (t < st) ired[t] += ired[t + st];
        __syncthreads();
    }
    const float cntf = (float)ired[0];

    if (t < 96) {
        float m2 = 0.f;
        for (int k = 0; k < NODE_IN; ++k) m2 = fmaf(acc[k], Wm[k * NODE_OUT + t], m2);
        molrow[t] = m2 + cntf * bm[t];
    } else if (t < 160) {
        const int j = t - 96;
        float m2 = 0.f;
        for (int k = 0; k < EDGE_IN; ++k) m2 = fmaf(acc[NODE_IN + k], We[k * EDGE_OUT + j], m2);
        molrow[t] = m2 + cntf * be[j];
    }
    __syncthreads();

    red[t] = (t < 160) ? molrow[t] : -1e30f;
    __syncthreads();
    for (int st = 128; st > 0; st >>= 1) {
        if (t < st) red[t] = fmaxf(red[t], red[t + st]);
        __syncthreads();
    }
    const float mx = red[0];
    __syncthreads();
    const float ev = (t < 160) ? expf(molrow[t] - mx) : 0.f;
    red[t] = ev;
    __syncthreads();
    for (int st = 128; st > 0; st >>= 1) {
        if (t < st) red[t] += red[t + st];
        __syncthreads();
    }
    if (t < 160) xbuf[(size_t)g * XDIM + t] = ev / red[0];
}

// ---------------- Kernel 3: fingerprint encoder -> x[:, 160:288] -------------
// 250 blocks x 256 threads; 2 rows/block; X in registers, broadcast by readlane.
__global__ __launch_bounds__(256) void fp_kernel(
    const float* __restrict__ fpv, const float* __restrict__ Wf,
    const float* __restrict__ bf, const float* __restrict__ gam,
    const float* __restrict__ bet, const float* __restrict__ mu,
    const float* __restrict__ var, float* __restrict__ xbuf)
{
    const int t = threadIdx.x;
    const int lane = t & 63;
    const int j = t & 127;          // output column
    const int r = t >> 7;           // 0/1 within block
    const int row = blockIdx.x * 2 + r;

    float a0 = 0.f, a1 = 0.f, a2 = 0.f, a3 = 0.f;
    float xc = fpv[(size_t)row * FPD + lane];          // chunk 0
    for (int k0 = 0; k0 < FPD; k0 += 64) {
        float xn = 0.f;
        if (k0 + 64 < FPD) xn = fpv[(size_t)row * FPD + k0 + 64 + lane];
        #pragma unroll
        for (int u = 0; u < 64; u += 4) {
            a0 = fmaf(rl_f(xc, u + 0), Wf[(size_t)(k0 + u + 0) * FPE + j], a0);
            a1 = fmaf(rl_f(xc, u + 1), Wf[(size_t)(k0 + u + 1) * FPE + j], a1);
            a2 = fmaf(rl_f(xc, u + 2), Wf[(size_t)(k0 + u + 2) * FPE + j], a2);
            a3 = fmaf(rl_f(xc, u + 3), Wf[(size_t)(k0 + u + 3) * FPE + j], a3);
        }
        xc = xn;
    }
    const float a = (a0 + a1) + (a2 + a3);
    const float sc = rsqrtf(var[j] + BN_EPS) * gam[j];
    const float sh = bet[j] - mu[j] * sc;
    const float y = fmaxf(fmaf(a + bf[j], sc, sh), 0.f);
    xbuf[(size_t)row * XDIM + 160 + j] = y;
}

// ---------------- Kernels 4-6: fp32 dense layers ------------------------------
// grid (ceil(Bv/16), No/64), 256 threads = 64 cols x 4 rowgroups x 4 rows.
// X rows live in registers; broadcast across cols via v_readlane.
__global__ __launch_bounds__(256) void ffn_kernel(
    const float* __restrict__ X, const float* __restrict__ W,
    const float* __restrict__ bias, float* __restrict__ Y,
    int Bv, int Ni, int No, int doRelu)
{
    const int t = threadIdx.x;
    const int lane = t & 63;
    const int col = blockIdx.y * 64 + lane;
    const int rg = t >> 6;                    // 0..3
    const int row0 = blockIdx.x * 16 + rg * 4;
    float acc0 = 0.f, acc1 = 0.f, acc2 = 0.f, acc3 = 0.f;

    float xc0, xc1, xc2, xc3;
    {
        const int ks = (Ni < 64) ? Ni : 64;
        xc0 = (row0 + 0 < Bv && lane < ks) ? X[(size_t)(row0 + 0) * Ni + lane] : 0.f;
        xc1 = (row0 + 1 < Bv && lane < ks) ? X[(size_t)(row0 + 1) * Ni + lane] : 0.f;
        xc2 = (row0 + 2 < Bv && lane < ks) ? X[(size_t)(row0 + 2) * Ni + lane] : 0.f;
        xc3 = (row0 + 3 < Bv && lane < ks) ? X[(size_t)(row0 + 3) * Ni + lane] : 0.f;
    }
    for (int k0 = 0; k0 < Ni; k0 += 64) {
        const int ks = (Ni - k0 < 64) ? (Ni - k0) : 64;
        float xn0 = 0.f, xn1 = 0.f, xn2 = 0.f, xn3 = 0.f;
        const int k1 = k0 + 64;
        if (k1 < Ni) {
            const int ks2 = (Ni - k1 < 64) ? (Ni - k1) : 64;
            xn0 = (row0 + 0 < Bv && lane < ks2) ? X[(size_t)(row0 + 0) * Ni + k1 + lane] : 0.f;
            xn1 = (row0 + 1 < Bv && lane < ks2) ? X[(size_t)(row0 + 1) * Ni + k1 + lane] : 0.f;
            xn2 = (row0 + 2 < Bv && lane < ks2) ? X[(size_t)(row0 + 2) * Ni + k1 + lane] : 0.f;
            xn3 = (row0 + 3 < Bv && lane < ks2) ? X[(size_t)(row0 + 3) * Ni + k1 + lane] : 0.f;
        }
        #pragma unroll 8
        for (int u = 0; u < ks; ++u) {
            const float w = W[(size_t)(k0 + u) * No + col];
            acc0 = fmaf(rl_f(xc0, u), w, acc0);
            acc1 = fmaf(rl_f(xc1, u), w, acc1);
            acc2 = fmaf(rl_f(xc2, u), w, acc2);
            acc3 = fmaf(rl_f(xc3, u), w, acc3);
        }
        xc0 = xn0; xc1 = xn1; xc2 = xn2; xc3 = xn3;
    }
    const float bv = bias[col];
    float o0 = acc0 + bv, o1 = acc1 + bv, o2 = acc2 + bv, o3 = acc3 + bv;
    if (doRelu) {
        o0 = fmaxf(o0, 0.f); o1 = fmaxf(o1, 0.f);
        o2 = fmaxf(o2, 0.f); o3 = fmaxf(o3, 0.f);
    }
    if (row0 + 0 < Bv) Y[(size_t)(row0 + 0) * No + col] = o0;
    if (row0 + 1 < Bv) Y[(size_t)(row0 + 1) * No + col] = o1;
    if (row0 + 2 < Bv) Y[(size_t)(row0 + 2) * No + col] = o2;
    if (row0 + 3 < Bv) Y[(size_t)(row0 + 3) * No + col] = o3;
}

extern "C" void kernel_launch(void* const* d_in, const int* in_sizes, int n_in,
                              void* d_out, int out_size, void* d_ws, size_t ws_size,
                              hipStream_t stream)
{
    const float* node_feats = (const float*)d_in[0];
    const float* edge_feats = (const float*)d_in[1];
    const float* fpv        = (const float*)d_in[2];
    const int*   src        = (const int*)d_in[3];
    const int*   dst        = (const int*)d_in[4];
    const int*   gids       = (const int*)d_in[5];
    const float* Wm  = (const float*)d_in[6];
    const float* bm  = (const float*)d_in[7];
    const float* We  = (const float*)d_in[8];
    const float* be  = (const float*)d_in[9];
    const float* Wf  = (const float*)d_in[10];
    const float* bf  = (const float*)d_in[11];
    const float* gam = (const float*)d_in[12];
    const float* bet = (const float*)d_in[13];
    const float* mu  = (const float*)d_in[14];
    const float* var = (const float*)d_in[15];
    const float* W0  = (const float*)d_in[16];
    const float* b0  = (const float*)d_in[17];
    const float* W1  = (const float*)d_in[18];
    const float* b1  = (const float*)d_in[19];
    const float* W2  = (const float*)d_in[20];
    const float* b2  = (const float*)d_in[21];
    const int E = in_sizes[3];

    float* xbuf = (float*)d_ws;                       // [500][288]
    float* h1   = xbuf + (size_t)NB * XDIM;           // [500][512]
    float* h2   = h1 + (size_t)NB * 512;              // [500][512]
    float* pf   = h2 + (size_t)NB * 512;              // [nblk][500][80]
    const size_t fixed = ((size_t)NB * XDIM + (size_t)NB * 512 * 2) * 4;
    long long avail = (long long)ws_size - (long long)fixed;
    int nblk = (int)(avail / (long long)((NB * ACC_W + NB) * 4));
    if (nblk > 256) nblk = 256;
    if (nblk < 8) nblk = 8;
    int* pi = (int*)(pf + (size_t)nblk * NB * ACC_W);

    hipLaunchKernelGGL(edge_scatter, dim3(nblk), dim3(1024), 0, stream,
                       node_feats, edge_feats, src, dst, gids, pf, pi, E);
    hipLaunchKernelGGL(mol_kernel, dim3(NB), dim3(256), 0, stream,
                       pf, pi, nblk, Wm, bm, We, be, xbuf);
    hipLaunchKernelGGL(fp_kernel, dim3(NB / 2), dim3(256), 0, stream,
                       fpv, Wf, bf, gam, bet, mu, var, xbuf);
    hipLaunchKernelGGL(ffn_kernel, dim3((NB + 15) / 16, 512 / 64), dim3(256), 0, stream,
                       xbuf, W0, b0, h1, NB, XDIM, 512, 1);
    hipLaunchKernelGGL(ffn_kernel, dim3((NB + 15) / 16, 512 / 64), dim3(256), 0, stream,
                       h1, W1, b1, h2, NB, 512, 512, 1);
    hipLaunchKernelGGL(ffn_kernel, dim3((NB + 15) / 16, 256 / 64), dim3(256), 0, stream,
                       h2, W2, b2, (float*)d_out, NB, 512, 256, 0);
}

// Round 3
// 442.990 us; speedup vs baseline: 1.3670x; 1.3670x over previous
//
#include <hip/hip_runtime.h>
#include <math.h>

#define NODE_IN 64
#define NODE_OUT 96
#define EDGE_IN 16
#define EDGE_OUT 64
#define ACC_W 80          // NODE_IN + EDGE_IN
#define NB 500            // graphs
#define FPD 2048
#define FPE 128
#define XDIM 288          // 160 + 128
#define BN_EPS 1e-5f

// ---------------- K1: edge graph keys + per-graph edge histogram -------------
__global__ __launch_bounds__(256) void key_hist(
    const int* __restrict__ dst, const int* __restrict__ gids,
    int* __restrict__ gkey, int* __restrict__ hist, int E)
{
    __shared__ int h[NB];
    for (int i = threadIdx.x; i < NB; i += 256) h[i] = 0;
    __syncthreads();
    const int stride = gridDim.x * 256;
    for (int e = blockIdx.x * 256 + threadIdx.x; e < E; e += stride) {
        const int g = gids[dst[e]];
        gkey[e] = g;
        atomicAdd(&h[g], 1);
    }
    __syncthreads();
    for (int i = threadIdx.x; i < NB; i += 256)
        if (h[i]) atomicAdd(&hist[i], h[i]);
}

// ---------------- K2: exclusive prefix sum over 500 counts -------------------
__global__ __launch_bounds__(512) void scan_kernel(
    const int* __restrict__ hist, int* __restrict__ offs, int* __restrict__ cursor)
{
    __shared__ int s[512];
    const int t = threadIdx.x;
    s[t] = (t < NB) ? hist[t] : 0;
    __syncthreads();
    for (int d = 1; d < 512; d <<= 1) {
        const int v = (t >= d) ? s[t - d] : 0;
        __syncthreads();
        s[t] += v;
        __syncthreads();
    }
    if (t < NB) {
        const int excl = s[t] - hist[t];
        offs[t] = excl;
        cursor[t] = excl;
    }
}

// ---------------- K3: bucket edges by graph ----------------------------------
__global__ __launch_bounds__(256) void scatter_kernel(
    const int* __restrict__ gkey, const int* __restrict__ src,
    int* __restrict__ cursor, int* __restrict__ ssrc, int* __restrict__ seid, int E)
{
    const int stride = gridDim.x * 256;
    for (int e = blockIdx.x * 256 + threadIdx.x; e < E; e += stride) {
        const int g = gkey[e];
        const int p = atomicAdd(&cursor[g], 1);
        ssrc[p] = src[e];
        seid[p] = e;
    }
}

// ---------------- K4: per-graph register accumulation + mol GEMM + softmax ---
__global__ __launch_bounds__(256) void graph_accum(
    const int* __restrict__ ssrc, const int* __restrict__ seid,
    const float* __restrict__ nf, const float* __restrict__ ef,
    const int* __restrict__ offs, const int* __restrict__ hist,
    const float* __restrict__ Wm, const float* __restrict__ bm,
    const float* __restrict__ We, const float* __restrict__ be,
    float* __restrict__ xbuf, int E)
{
    const int g = blockIdx.x;
    const int t = threadIdx.x;
    const int lane = t & 63;
    const int w = t >> 6;
    const int start = offs[g];
    const int cnt = hist[g];
    const int end = start + cnt;
    const int q = lane >> 4, c = lane & 15;

    __shared__ float sacc[4][ACC_W];
    __shared__ float accRow[ACC_W];
    __shared__ float red[256];

    float nacc = 0.f;   // node part: this lane owns feature column `lane`
    float eacc = 0.f;   // edge part: column c, quarter q

    for (int p0 = start + w * 64; p0 < end; p0 += 256) {
        const int lim = min(64, end - p0);
        // coalesced index loads for this 64-edge batch (clamped, masked later)
        const int sv = ssrc[min(p0 + lane, E - 1)];
        const int ev = seid[min(p0 + lane, E - 1)];

        // node rows: 16 independent gather loads in flight, register adds
        #pragma unroll
        for (int u0 = 0; u0 < 64; u0 += 16) {
            float v[16];
            #pragma unroll
            for (int u = 0; u < 16; ++u) {
                const int s = __builtin_amdgcn_readlane(sv, u0 + u);
                v[u] = nf[(size_t)s * NODE_IN + lane];
            }
            #pragma unroll
            for (int u = 0; u < 16; ++u)
                nacc += (u0 + u < lim) ? v[u] : 0.f;
        }

        // edge rows: 4 edges x 16 cols per step, eid via bpermute broadcast
        #pragma unroll
        for (int u0 = 0; u0 < 16; u0 += 8) {
            float w8[8];
            int idx8[8];
            #pragma unroll
            for (int u = 0; u < 8; ++u) {
                const int idx = (u0 + u) * 4 + q;
                const int eid = __shfl(ev, idx);
                idx8[u] = idx;
                w8[u] = ef[(size_t)eid * EDGE_IN + c];
            }
            #pragma unroll
            for (int u = 0; u < 8; ++u)
                eacc += (idx8[u] < lim) ? w8[u] : 0.f;
        }
    }

    if (lane < NODE_IN) sacc[w][lane] = nacc;
    eacc += __shfl_xor(eacc, 16);
    eacc += __shfl_xor(eacc, 32);
    if (lane < EDGE_IN) sacc[w][NODE_IN + lane] = eacc;
    __syncthreads();
    if (t < ACC_W) accRow[t] = (sacc[0][t] + sacc[1][t]) + (sacc[2][t] + sacc[3][t]);
    __syncthreads();

    // tiny GEMMs: [80] -> [160] molrow, plus count-scaled biases
    const float cntf = (float)cnt;
    float mr = 0.f;
    if (t < 96) {
        float m2 = 0.f;
        for (int k = 0; k < NODE_IN; ++k) m2 = fmaf(accRow[k], Wm[k * NODE_OUT + t], m2);
        mr = m2 + cntf * bm[t];
    } else if (t < 160) {
        const int j = t - 96;
        float m2 = 0.f;
        for (int k = 0; k < EDGE_IN; ++k) m2 = fmaf(accRow[NODE_IN + k], We[k * EDGE_OUT + j], m2);
        mr = m2 + cntf * be[j];
    }

    // softmax over the 160 mol columns
    red[t] = (t < 160) ? mr : -1e30f;
    __syncthreads();
    for (int st = 128; st > 0; st >>= 1) {
        if (t < st) red[t] = fmaxf(red[t], red[t + st]);
        __syncthreads();
    }
    const float mx = red[0];
    __syncthreads();
    const float evx = (t < 160) ? expf(mr - mx) : 0.f;
    red[t] = evx;
    __syncthreads();
    for (int st = 128; st > 0; st >>= 1) {
        if (t < st) red[t] += red[t + st];
        __syncthreads();
    }
    if (t < 160) xbuf[(size_t)g * XDIM + t] = evx / red[0];
}

// ---------------- K5: fingerprint encoder -> x[:, 160:288] -------------------
__global__ __launch_bounds__(256) void fp_kernel(
    const float* __restrict__ fpv, const float* __restrict__ Wf,
    const float* __restrict__ bf, const float* __restrict__ gam,
    const float* __restrict__ bet, const float* __restrict__ mu,
    const float* __restrict__ var, float* __restrict__ xbuf)
{
    __shared__ float xs[2][FPD];
    const int t = threadIdx.x;
    const int r0 = blockIdx.x * 2;
    for (int i = t; i < 2 * FPD / 4; i += 256)
        ((float4*)xs)[i] = ((const float4*)(fpv + (size_t)r0 * FPD))[i];
    __syncthreads();

    const int j = t & 127, r = t >> 7;
    const float* xr = xs[r];
    float a0 = 0.f, a1 = 0.f, a2 = 0.f, a3 = 0.f;
    for (int k = 0; k < FPD; k += 4) {
        const float4 x4 = *(const float4*)&xr[k];
        a0 = fmaf(x4.x, Wf[(size_t)(k + 0) * FPE + j], a0);
        a1 = fmaf(x4.y, Wf[(size_t)(k + 1) * FPE + j], a1);
        a2 = fmaf(x4.z, Wf[(size_t)(k + 2) * FPE + j], a2);
        a3 = fmaf(x4.w, Wf[(size_t)(k + 3) * FPE + j], a3);
    }
    const float a = (a0 + a1) + (a2 + a3);
    const float sc = rsqrtf(var[j] + BN_EPS) * gam[j];
    const float sh = bet[j] - mu[j] * sc;
    xbuf[(size_t)(r0 + r) * XDIM + 160 + j] = fmaxf(fmaf(a + bf[j], sc, sh), 0.f);
}

// ---------------- K6-K8: fp32 tile GEMM (64x64 tile, 4x4 per thread) ---------
__global__ __launch_bounds__(256) void ffn_kernel(
    const float* __restrict__ X, const float* __restrict__ W,
    const float* __restrict__ bias, float* __restrict__ Y,
    int Bv, int Ni, int No, int doRelu)
{
    __shared__ float Xs[16][68];
    __shared__ float Ws[16][68];
    const int t = threadIdx.x;
    const int m0 = (t & 15) * 4, n0 = (t >> 4) * 4;
    const int rowBase = blockIdx.x * 64, colBase = blockIdx.y * 64;
    float acc[4][4] = {};

    for (int k0 = 0; k0 < Ni; k0 += 16) {
        for (int i = t; i < 1024; i += 256) {
            const int m = i >> 4, k = i & 15;
            const int row = rowBase + m;
            Xs[k][m] = (row < Bv) ? X[(size_t)row * Ni + k0 + k] : 0.f;
        }
        for (int i = t; i < 1024; i += 256) {
            const int k = i >> 6, n = i & 63;
            Ws[k][n] = W[(size_t)(k0 + k) * No + colBase + n];
        }
        __syncthreads();
        #pragma unroll
        for (int k = 0; k < 16; ++k) {
            const float4 a4 = *(const float4*)&Xs[k][m0];
            const float4 b4 = *(const float4*)&Ws[k][n0];
            acc[0][0] = fmaf(a4.x, b4.x, acc[0][0]);
            acc[0][1] = fmaf(a4.x, b4.y, acc[0][1]);
            acc[0][2] = fmaf(a4.x, b4.z, acc[0][2]);
            acc[0][3] = fmaf(a4.x, b4.w, acc[0][3]);
            acc[1][0] = fmaf(a4.y, b4.x, acc[1][0]);
            acc[1][1] = fmaf(a4.y, b4.y, acc[1][1]);
            acc[1][2] = fmaf(a4.y, b4.z, acc[1][2]);
            acc[1][3] = fmaf(a4.y, b4.w, acc[1][3]);
            acc[2][0] = fmaf(a4.z, b4.x, acc[2][0]);
            acc[2][1] = fmaf(a4.z, b4.y, acc[2][1]);
            acc[2][2] = fmaf(a4.z, b4.z, acc[2][2]);
            acc[2][3] = fmaf(a4.z, b4.w, acc[2][3]);
            acc[3][0] = fmaf(a4.w, b4.x, acc[3][0]);
            acc[3][1] = fmaf(a4.w, b4.y, acc[3][1]);
            acc[3][2] = fmaf(a4.w, b4.z, acc[3][2]);
            acc[3][3] = fmaf(a4.w, b4.w, acc[3][3]);
        }
        __syncthreads();
    }

    #pragma unroll
    for (int mm = 0; mm < 4; ++mm) {
        const int row = rowBase + m0 + mm;
        if (row < Bv) {
            float4 o;
            o.x = acc[mm][0] + bias[colBase + n0 + 0];
            o.y = acc[mm][1] + bias[colBase + n0 + 1];
            o.z = acc[mm][2] + bias[colBase + n0 + 2];
            o.w = acc[mm][3] + bias[colBase + n0 + 3];
            if (doRelu) {
                o.x = fmaxf(o.x, 0.f); o.y = fmaxf(o.y, 0.f);
                o.z = fmaxf(o.z, 0.f); o.w = fmaxf(o.w, 0.f);
            }
            *(float4*)&Y[(size_t)row * No + colBase + n0] = o;
        }
    }
}

extern "C" void kernel_launch(void* const* d_in, const int* in_sizes, int n_in,
                              void* d_out, int out_size, void* d_ws, size_t ws_size,
                              hipStream_t stream)
{
    const float* node_feats = (const float*)d_in[0];
    const float* edge_feats = (const float*)d_in[1];
    const float* fpv        = (const float*)d_in[2];
    const int*   src        = (const int*)d_in[3];
    const int*   dst        = (const int*)d_in[4];
    const int*   gids       = (const int*)d_in[5];
    const float* Wm  = (const float*)d_in[6];
    const float* bm  = (const float*)d_in[7];
    const float* We  = (const float*)d_in[8];
    const float* be  = (const float*)d_in[9];
    const float* Wf  = (const float*)d_in[10];
    const float* bf  = (const float*)d_in[11];
    const float* gam = (const float*)d_in[12];
    const float* bet = (const float*)d_in[13];
    const float* mu  = (const float*)d_in[14];
    const float* var = (const float*)d_in[15];
    const float* W0  = (const float*)d_in[16];
    const float* b0  = (const float*)d_in[17];
    const float* W1  = (const float*)d_in[18];
    const float* b1  = (const float*)d_in[19];
    const float* W2  = (const float*)d_in[20];
    const float* b2  = (const float*)d_in[21];
    const int E = in_sizes[3];

    // workspace layout
    float* xbuf = (float*)d_ws;                         // [500][288]
    float* h1   = xbuf + (size_t)NB * XDIM;             // [500][512]
    float* h2   = h1 + (size_t)NB * 512;                // [500][512]
    int*   gkey = (int*)(h2 + (size_t)NB * 512);        // [E]
    int*   ssrc = gkey + E;                              // [E]
    int*   seid = ssrc + E;                              // [E]
    int*   hist = seid + E;                              // [500]
    int*   offs = hist + NB;                             // [500]
    int*   curs = offs + NB;                             // [500]

    hipMemsetAsync(hist, 0, NB * sizeof(int), stream);
    hipLaunchKernelGGL(key_hist, dim3(256), dim3(256), 0, stream,
                       dst, gids, gkey, hist, E);
    hipLaunchKernelGGL(scan_kernel, dim3(1), dim3(512), 0, stream,
                       hist, offs, curs);
    hipLaunchKernelGGL(scatter_kernel, dim3(512), dim3(256), 0, stream,
                       gkey, src, curs, ssrc, seid, E);
    hipLaunchKernelGGL(graph_accum, dim3(NB), dim3(256), 0, stream,
                       ssrc, seid, node_feats, edge_feats, offs, hist,
                       Wm, bm, We, be, xbuf, E);
    hipLaunchKernelGGL(fp_kernel, dim3(NB / 2), dim3(256), 0, stream,
                       fpv, Wf, bf, gam, bet, mu, var, xbuf);
    hipLaunchKernelGGL(ffn_kernel, dim3((NB + 63) / 64, 512 / 64), dim3(256), 0, stream,
                       xbuf, W0, b0, h1, NB, XDIM, 512, 1);
    hipLaunchKernelGGL(ffn_kernel, dim3((NB + 63) / 64, 512 / 64), dim3(256), 0, stream,
                       h1, W1, b1, h2, NB, 512, 512, 1);
    hipLaunchKernelGGL(ffn_kernel, dim3((NB + 63) / 64, 256 / 64), dim3(256), 0, stream,
                       h2, W2, b2, (float*)d_out, NB, 512, 256, 0);
}

// Round 4
// 310.446 us; speedup vs baseline: 1.9506x; 1.4269x over previous
//
#include <hip/hip_runtime.h>
#include <math.h>

#define NODE_IN 64
#define NODE_OUT 96
#define EDGE_IN 16
#define EDGE_OUT 64
#define ACC_W 80          // NODE_IN + EDGE_IN
#define NB 500            // graphs
#define FPD 2048
#define FPE 128
#define XDIM 288          // 160 + 128
#define BN_EPS 1e-5f
#define HP 32             // per-graph counter padding (32 ints = 128 B line)

// ---------------- K1: edge graph keys + per-graph edge histogram (padded) ----
__global__ __launch_bounds__(256) void key_hist(
    const int* __restrict__ dst, const int* __restrict__ gids,
    int* __restrict__ gkey, int* __restrict__ histP, int E)
{
    __shared__ int h[NB];
    for (int i = threadIdx.x; i < NB; i += 256) h[i] = 0;
    __syncthreads();
    const int stride = gridDim.x * 256;
    for (int e = blockIdx.x * 256 + threadIdx.x; e < E; e += stride) {
        const int g = gids[dst[e]];
        gkey[e] = g;
        atomicAdd(&h[g], 1);
    }
    __syncthreads();
    for (int i = threadIdx.x; i < NB; i += 256)
        if (h[i]) atomicAdd(&histP[i * HP], h[i]);
}

// ---------------- K2: exclusive prefix sum over 500 padded counts ------------
__global__ __launch_bounds__(512) void scan_kernel(
    const int* __restrict__ histP, int* __restrict__ offs, int* __restrict__ cursP)
{
    __shared__ int s[512];
    const int t = threadIdx.x;
    const int v0 = (t < NB) ? histP[t * HP] : 0;
    s[t] = v0;
    __syncthreads();
    for (int d = 1; d < 512; d <<= 1) {
        const int v = (t >= d) ? s[t - d] : 0;
        __syncthreads();
        s[t] += v;
        __syncthreads();
    }
    if (t < NB) {
        offs[t] = s[t] - v0;
        cursP[t * HP] = s[t] - v0;
    }
}

// ---------------- K3: bucket edges by graph (block-aggregated atomics) -------
__global__ __launch_bounds__(256) void scatter_kernel(
    const int* __restrict__ gkey, const int* __restrict__ src,
    int* __restrict__ cursP, int* __restrict__ ssrc, int* __restrict__ seid, int E)
{
    __shared__ int h[NB];
    __shared__ int base[NB];
    const int t = threadIdx.x;
    for (int i = t; i < NB; i += 256) h[i] = 0;
    __syncthreads();

    const int e0 = blockIdx.x * 1024;
    int g4[4], lr4[4];
    #pragma unroll
    for (int i = 0; i < 4; ++i) {
        const int e = e0 + i * 256 + t;
        g4[i] = -1; lr4[i] = 0;
        if (e < E) {
            g4[i] = gkey[e];
            lr4[i] = atomicAdd(&h[g4[i]], 1);   // local rank within block
        }
    }
    __syncthreads();
    for (int i = t; i < NB; i += 256)
        base[i] = (h[i] > 0) ? atomicAdd(&cursP[i * HP], h[i]) : 0;
    __syncthreads();
    #pragma unroll
    for (int i = 0; i < 4; ++i) {
        const int e = e0 + i * 256 + t;
        if (g4[i] >= 0) {
            const int p = base[g4[i]] + lr4[i];
            ssrc[p] = src[e];
            seid[p] = e;
        }
    }
}

// ---------------- K4: per-graph register accumulation + mol GEMM + softmax ---
__global__ __launch_bounds__(256) void graph_accum(
    const int* __restrict__ ssrc, const int* __restrict__ seid,
    const float* __restrict__ nf, const float* __restrict__ ef,
    const int* __restrict__ offs, const int* __restrict__ histP,
    const float* __restrict__ Wm, const float* __restrict__ bm,
    const float* __restrict__ We, const float* __restrict__ be,
    float* __restrict__ xbuf, int E)
{
    const int g = blockIdx.x;
    const int t = threadIdx.x;
    const int lane = t & 63;
    const int w = t >> 6;
    const int start = offs[g];
    const int cnt = histP[g * HP];
    const int end = start + cnt;
    const int q = lane >> 4, c = lane & 15;

    __shared__ float sacc[4][ACC_W];
    __shared__ float accRow[ACC_W];
    __shared__ float red[256];

    float nacc = 0.f;   // node part: this lane owns feature column `lane`
    float eacc = 0.f;   // edge part: column c, quarter q

    for (int p0 = start + w * 64; p0 < end; p0 += 256) {
        const int lim = min(64, end - p0);
        const int sv = ssrc[min(p0 + lane, E - 1)];
        const int ev = seid[min(p0 + lane, E - 1)];

        // node rows: 16 independent gather loads in flight, register adds
        #pragma unroll
        for (int u0 = 0; u0 < 64; u0 += 16) {
            float v[16];
            #pragma unroll
            for (int u = 0; u < 16; ++u) {
                const int s = __builtin_amdgcn_readlane(sv, u0 + u);
                v[u] = nf[(size_t)s * NODE_IN + lane];
            }
            #pragma unroll
            for (int u = 0; u < 16; ++u)
                nacc += (u0 + u < lim) ? v[u] : 0.f;
        }

        // edge rows: 4 edges x 16 cols per step, 8-deep pipelined
        #pragma unroll
        for (int u0 = 0; u0 < 16; u0 += 8) {
            float w8[8];
            int idx8[8];
            #pragma unroll
            for (int u = 0; u < 8; ++u) {
                const int idx = (u0 + u) * 4 + q;
                const int eid = __shfl(ev, idx);
                idx8[u] = idx;
                w8[u] = ef[(size_t)eid * EDGE_IN + c];
            }
            #pragma unroll
            for (int u = 0; u < 8; ++u)
                eacc += (idx8[u] < lim) ? w8[u] : 0.f;
        }
    }

    if (lane < NODE_IN) sacc[w][lane] = nacc;
    eacc += __shfl_xor(eacc, 16);
    eacc += __shfl_xor(eacc, 32);
    if (lane < EDGE_IN) sacc[w][NODE_IN + lane] = eacc;
    __syncthreads();
    if (t < ACC_W) accRow[t] = (sacc[0][t] + sacc[1][t]) + (sacc[2][t] + sacc[3][t]);
    __syncthreads();

    // tiny GEMMs: [80] -> [160] molrow, plus count-scaled biases
    const float cntf = (float)cnt;
    float mr = 0.f;
    if (t < 96) {
        float m2 = 0.f;
        for (int k = 0; k < NODE_IN; ++k) m2 = fmaf(accRow[k], Wm[k * NODE_OUT + t], m2);
        mr = m2 + cntf * bm[t];
    } else if (t < 160) {
        const int j = t - 96;
        float m2 = 0.f;
        for (int k = 0; k < EDGE_IN; ++k) m2 = fmaf(accRow[NODE_IN + k], We[k * EDGE_OUT + j], m2);
        mr = m2 + cntf * be[j];
    }

    // softmax over the 160 mol columns
    red[t] = (t < 160) ? mr : -1e30f;
    __syncthreads();
    for (int st = 128; st > 0; st >>= 1) {
        if (t < st) red[t] = fmaxf(red[t], red[t + st]);
        __syncthreads();
    }
    const float mx = red[0];
    __syncthreads();
    const float evx = (t < 160) ? expf(mr - mx) : 0.f;
    red[t] = evx;
    __syncthreads();
    for (int st = 128; st > 0; st >>= 1) {
        if (t < st) red[t] += red[t + st];
        __syncthreads();
    }
    if (t < 160) xbuf[(size_t)g * XDIM + t] = evx / red[0];
}

// ---------------- K5: fingerprint encoder -> x[:, 160:288] -------------------
__global__ __launch_bounds__(256) void fp_kernel(
    const float* __restrict__ fpv, const float* __restrict__ Wf,
    const float* __restrict__ bf, const float* __restrict__ gam,
    const float* __restrict__ bet, const float* __restrict__ mu,
    const float* __restrict__ var, float* __restrict__ xbuf)
{
    __shared__ float xs[2][FPD];
    const int t = threadIdx.x;
    const int r0 = blockIdx.x * 2;
    for (int i = t; i < 2 * FPD / 4; i += 256)
        ((float4*)xs)[i] = ((const float4*)(fpv + (size_t)r0 * FPD))[i];
    __syncthreads();

    const int j = t & 127, r = t >> 7;
    const float* xr = xs[r];
    float a0 = 0.f, a1 = 0.f, a2 = 0.f, a3 = 0.f;
    for (int k = 0; k < FPD; k += 4) {
        const float4 x4 = *(const float4*)&xr[k];
        a0 = fmaf(x4.x, Wf[(size_t)(k + 0) * FPE + j], a0);
        a1 = fmaf(x4.y, Wf[(size_t)(k + 1) * FPE + j], a1);
        a2 = fmaf(x4.z, Wf[(size_t)(k + 2) * FPE + j], a2);
        a3 = fmaf(x4.w, Wf[(size_t)(k + 3) * FPE + j], a3);
    }
    const float a = (a0 + a1) + (a2 + a3);
    const float sc = rsqrtf(var[j] + BN_EPS) * gam[j];
    const float sh = bet[j] - mu[j] * sc;
    xbuf[(size_t)(r0 + r) * XDIM + 160 + j] = fmaxf(fmaf(a + bf[j], sc, sh), 0.f);
}

// ---------------- K6-K8: fp32 tile GEMM (64x64 tile, 4x4 per thread) ---------
__global__ __launch_bounds__(256) void ffn_kernel(
    const float* __restrict__ X, const float* __restrict__ W,
    const float* __restrict__ bias, float* __restrict__ Y,
    int Bv, int Ni, int No, int doRelu)
{
    __shared__ float Xs[16][68];
    __shared__ float Ws[16][68];
    const int t = threadIdx.x;
    const int m0 = (t & 15) * 4, n0 = (t >> 4) * 4;
    const int rowBase = blockIdx.x * 64, colBase = blockIdx.y * 64;
    float acc[4][4] = {};

    for (int k0 = 0; k0 < Ni; k0 += 16) {
        for (int i = t; i < 1024; i += 256) {
            const int m = i >> 4, k = i & 15;
            const int row = rowBase + m;
            Xs[k][m] = (row < Bv) ? X[(size_t)row * Ni + k0 + k] : 0.f;
        }
        for (int i = t; i < 1024; i += 256) {
            const int k = i >> 6, n = i & 63;
            Ws[k][n] = W[(size_t)(k0 + k) * No + colBase + n];
        }
        __syncthreads();
        #pragma unroll
        for (int k = 0; k < 16; ++k) {
            const float4 a4 = *(const float4*)&Xs[k][m0];
            const float4 b4 = *(const float4*)&Ws[k][n0];
            acc[0][0] = fmaf(a4.x, b4.x, acc[0][0]);
            acc[0][1] = fmaf(a4.x, b4.y, acc[0][1]);
            acc[0][2] = fmaf(a4.x, b4.z, acc[0][2]);
            acc[0][3] = fmaf(a4.x, b4.w, acc[0][3]);
            acc[1][0] = fmaf(a4.y, b4.x, acc[1][0]);
            acc[1][1] = fmaf(a4.y, b4.y, acc[1][1]);
            acc[1][2] = fmaf(a4.y, b4.z, acc[1][2]);
            acc[1][3] = fmaf(a4.y, b4.w, acc[1][3]);
            acc[2][0] = fmaf(a4.z, b4.x, acc[2][0]);
            acc[2][1] = fmaf(a4.z, b4.y, acc[2][1]);
            acc[2][2] = fmaf(a4.z, b4.z, acc[2][2]);
            acc[2][3] = fmaf(a4.z, b4.w, acc[2][3]);
            acc[3][0] = fmaf(a4.w, b4.x, acc[3][0]);
            acc[3][1] = fmaf(a4.w, b4.y, acc[3][1]);
            acc[3][2] = fmaf(a4.w, b4.z, acc[3][2]);
            acc[3][3] = fmaf(a4.w, b4.w, acc[3][3]);
        }
        __syncthreads();
    }

    #pragma unroll
    for (int mm = 0; mm < 4; ++mm) {
        const int row = rowBase + m0 + mm;
        if (row < Bv) {
            float4 o;
            o.x = acc[mm][0] + bias[colBase + n0 + 0];
            o.y = acc[mm][1] + bias[colBase + n0 + 1];
            o.z = acc[mm][2] + bias[colBase + n0 + 2];
            o.w = acc[mm][3] + bias[colBase + n0 + 3];
            if (doRelu) {
                o.x = fmaxf(o.x, 0.f); o.y = fmaxf(o.y, 0.f);
                o.z = fmaxf(o.z, 0.f); o.w = fmaxf(o.w, 0.f);
            }
            *(float4*)&Y[(size_t)row * No + colBase + n0] = o;
        }
    }
}

extern "C" void kernel_launch(void* const* d_in, const int* in_sizes, int n_in,
                              void* d_out, int out_size, void* d_ws, size_t ws_size,
                              hipStream_t stream)
{
    const float* node_feats = (const float*)d_in[0];
    const float* edge_feats = (const float*)d_in[1];
    const float* fpv        = (const float*)d_in[2];
    const int*   src        = (const int*)d_in[3];
    const int*   dst        = (const int*)d_in[4];
    const int*   gids       = (const int*)d_in[5];
    const float* Wm  = (const float*)d_in[6];
    const float* bm  = (const float*)d_in[7];
    const float* We  = (const float*)d_in[8];
    const float* be  = (const float*)d_in[9];
    const float* Wf  = (const float*)d_in[10];
    const float* bf  = (const float*)d_in[11];
    const float* gam = (const float*)d_in[12];
    const float* bet = (const float*)d_in[13];
    const float* mu  = (const float*)d_in[14];
    const float* var = (const float*)d_in[15];
    const float* W0  = (const float*)d_in[16];
    const float* b0  = (const float*)d_in[17];
    const float* W1  = (const float*)d_in[18];
    const float* b1  = (const float*)d_in[19];
    const float* W2  = (const float*)d_in[20];
    const float* b2  = (const float*)d_in[21];
    const int E = in_sizes[3];

    // workspace layout
    float* xbuf  = (float*)d_ws;                         // [500][288]
    float* h1    = xbuf + (size_t)NB * XDIM;             // [500][512]
    float* h2    = h1 + (size_t)NB * 512;                // [500][512]
    int*   gkey  = (int*)(h2 + (size_t)NB * 512);        // [E]
    int*   ssrc  = gkey + E;                              // [E]
    int*   seid  = ssrc + E;                              // [E]
    int*   histP = seid + E;                              // [NB*HP] padded
    int*   offs  = histP + NB * HP;                       // [NB]
    int*   cursP = offs + NB;                             // [NB*HP] padded

    hipMemsetAsync(histP, 0, NB * HP * sizeof(int), stream);
    hipLaunchKernelGGL(key_hist, dim3(256), dim3(256), 0, stream,
                       dst, gids, gkey, histP, E);
    hipLaunchKernelGGL(scan_kernel, dim3(1), dim3(512), 0, stream,
                       histP, offs, cursP);
    hipLaunchKernelGGL(scatter_kernel, dim3((E + 1023) / 1024), dim3(256), 0, stream,
                       gkey, src, cursP, ssrc, seid, E);
    hipLaunchKernelGGL(graph_accum, dim3(NB), dim3(256), 0, stream,
                       ssrc, seid, node_feats, edge_feats, offs, histP,
                       Wm, bm, We, be, xbuf, E);
    hipLaunchKernelGGL(fp_kernel, dim3(NB / 2), dim3(256), 0, stream,
                       fpv, Wf, bf, gam, bet, mu, var, xbuf);
    hipLaunchKernelGGL(ffn_kernel, dim3((NB + 63) / 64, 512 / 64), dim3(256), 0, stream,
                       xbuf, W0, b0, h1, NB, XDIM, 512, 1);
    hipLaunchKernelGGL(ffn_kernel, dim3((NB + 63) / 64, 512 / 64), dim3(256), 0, stream,
                       h1, W1, b1, h2, NB, 512, 512, 1);
    hipLaunchKernelGGL(ffn_kernel, dim3((NB + 63) / 64, 256 / 64), dim3(256), 0, stream,
                       h2, W2, b2, (float*)d_out, NB, 512, 256, 0);
}

// Round 5
// 196.097 us; speedup vs baseline: 3.0880x; 1.5831x over previous
//
#include <hip/hip_runtime.h>
#include <math.h>

#define NODE_IN 64
#define NODE_OUT 96
#define EDGE_IN 16
#define EDGE_OUT 64
#define ACC_W 80          // NODE_IN + EDGE_IN
#define NB 500            // graphs
#define FPD 2048
#define FPE 128
#define XDIM 288          // 160 + 128
#define BN_EPS 1e-5f
#define HP 32             // per-graph counter padding (32 ints = 128 B line)

// ---------------- K1: edge graph keys + per-graph edge histogram (padded) ----
__global__ __launch_bounds__(256) void key_hist(
    const int* __restrict__ dst, const int* __restrict__ gids,
    int* __restrict__ gkey, int* __restrict__ histP, int E)
{
    __shared__ int h[NB];
    for (int i = threadIdx.x; i < NB; i += 256) h[i] = 0;
    __syncthreads();
    const int stride = gridDim.x * 256;
    for (int e = blockIdx.x * 256 + threadIdx.x; e < E; e += stride) {
        const int g = gids[dst[e]];
        gkey[e] = g;
        atomicAdd(&h[g], 1);
    }
    __syncthreads();
    for (int i = threadIdx.x; i < NB; i += 256)
        if (h[i]) atomicAdd(&histP[i * HP], h[i]);
}

// ---------------- K2: exclusive prefix sum over 500 padded counts ------------
__global__ __launch_bounds__(512) void scan_kernel(
    const int* __restrict__ histP, int* __restrict__ offs, int* __restrict__ cursP)
{
    __shared__ int s[512];
    const int t = threadIdx.x;
    const int v0 = (t < NB) ? histP[t * HP] : 0;
    s[t] = v0;
    __syncthreads();
    for (int d = 1; d < 512; d <<= 1) {
        const int v = (t >= d) ? s[t - d] : 0;
        __syncthreads();
        s[t] += v;
        __syncthreads();
    }
    if (t < NB) {
        offs[t] = s[t] - v0;
        cursP[t * HP] = s[t] - v0;
    }
}

// ---------------- K3: bucket edges by graph (block-aggregated atomics) -------
__global__ __launch_bounds__(256) void scatter_kernel(
    const int* __restrict__ gkey, const int* __restrict__ src,
    int* __restrict__ cursP, int* __restrict__ ssrc, int* __restrict__ seid, int E)
{
    __shared__ int h[NB];
    __shared__ int base[NB];
    const int t = threadIdx.x;
    for (int i = t; i < NB; i += 256) h[i] = 0;
    __syncthreads();

    const int e0 = blockIdx.x * 1024;
    int g4[4], lr4[4];
    #pragma unroll
    for (int i = 0; i < 4; ++i) {
        const int e = e0 + i * 256 + t;
        g4[i] = -1; lr4[i] = 0;
        if (e < E) {
            g4[i] = gkey[e];
            lr4[i] = atomicAdd(&h[g4[i]], 1);   // local rank within block
        }
    }
    __syncthreads();
    for (int i = t; i < NB; i += 256)
        base[i] = (h[i] > 0) ? atomicAdd(&cursP[i * HP], h[i]) : 0;
    __syncthreads();
    #pragma unroll
    for (int i = 0; i < 4; ++i) {
        const int e = e0 + i * 256 + t;
        if (g4[i] >= 0) {
            const int p = base[g4[i]] + lr4[i];
            ssrc[p] = src[e];
            seid[p] = e;
        }
    }
}

// ---------------- K4: per-graph register accumulation + mol GEMM + softmax ---
__global__ __launch_bounds__(256) void graph_accum(
    const int* __restrict__ ssrc, const int* __restrict__ seid,
    const float* __restrict__ nf, const float* __restrict__ ef,
    const int* __restrict__ offs, const int* __restrict__ histP,
    const float* __restrict__ Wm, const float* __restrict__ bm,
    const float* __restrict__ We, const float* __restrict__ be,
    float* __restrict__ xbuf, int E)
{
    const int g = blockIdx.x;
    const int t = threadIdx.x;
    const int lane = t & 63;
    const int w = t >> 6;
    const int start = offs[g];
    const int cnt = histP[g * HP];
    const int end = start + cnt;
    const int q = lane >> 4, c = lane & 15;

    __shared__ float sacc[4][ACC_W];
    __shared__ float accRow[ACC_W];
    __shared__ float red[256];

    float nacc = 0.f;   // node part: this lane owns feature column `lane`
    float eacc = 0.f;   // edge part: column c, quarter q

    for (int p0 = start + w * 64; p0 < end; p0 += 256) {
        const int lim = min(64, end - p0);
        const int sv = ssrc[min(p0 + lane, E - 1)];
        const int ev = seid[min(p0 + lane, E - 1)];

        // node rows: 16 independent gather loads in flight, register adds
        #pragma unroll
        for (int u0 = 0; u0 < 64; u0 += 16) {
            float v[16];
            #pragma unroll
            for (int u = 0; u < 16; ++u) {
                const int s = __builtin_amdgcn_readlane(sv, u0 + u);
                v[u] = nf[(size_t)s * NODE_IN + lane];
            }
            #pragma unroll
            for (int u = 0; u < 16; ++u)
                nacc += (u0 + u < lim) ? v[u] : 0.f;
        }

        // edge rows: 4 edges x 16 cols per step, 8-deep pipelined
        #pragma unroll
        for (int u0 = 0; u0 < 16; u0 += 8) {
            float w8[8];
            int idx8[8];
            #pragma unroll
            for (int u = 0; u < 8; ++u) {
                const int idx = (u0 + u) * 4 + q;
                const int eid = __shfl(ev, idx);
                idx8[u] = idx;
                w8[u] = ef[(size_t)eid * EDGE_IN + c];
            }
            #pragma unroll
            for (int u = 0; u < 8; ++u)
                eacc += (idx8[u] < lim) ? w8[u] : 0.f;
        }
    }

    if (lane < NODE_IN) sacc[w][lane] = nacc;
    eacc += __shfl_xor(eacc, 16);
    eacc += __shfl_xor(eacc, 32);
    if (lane < EDGE_IN) sacc[w][NODE_IN + lane] = eacc;
    __syncthreads();
    if (t < ACC_W) accRow[t] = (sacc[0][t] + sacc[1][t]) + (sacc[2][t] + sacc[3][t]);
    __syncthreads();

    // tiny GEMMs: [80] -> [160] molrow, plus count-scaled biases
    const float cntf = (float)cnt;
    float mr = 0.f;
    if (t < 96) {
        float m2 = 0.f;
        for (int k = 0; k < NODE_IN; ++k) m2 = fmaf(accRow[k], Wm[k * NODE_OUT + t], m2);
        mr = m2 + cntf * bm[t];
    } else if (t < 160) {
        const int j = t - 96;
        float m2 = 0.f;
        for (int k = 0; k < EDGE_IN; ++k) m2 = fmaf(accRow[NODE_IN + k], We[k * EDGE_OUT + j], m2);
        mr = m2 + cntf * be[j];
    }

    // softmax over the 160 mol columns
    red[t] = (t < 160) ? mr : -1e30f;
    __syncthreads();
    for (int st = 128; st > 0; st >>= 1) {
        if (t < st) red[t] = fmaxf(red[t], red[t + st]);
        __syncthreads();
    }
    const float mx = red[0];
    __syncthreads();
    const float evx = (t < 160) ? expf(mr - mx) : 0.f;
    red[t] = evx;
    __syncthreads();
    for (int st = 128; st > 0; st >>= 1) {
        if (t < st) red[t] += red[t + st];
        __syncthreads();
    }
    if (t < 160) xbuf[(size_t)g * XDIM + t] = evx / red[0];
}

// ---------------- K5: fingerprint encoder -> x[:, 160:288] -------------------
__global__ __launch_bounds__(256) void fp_kernel(
    const float* __restrict__ fpv, const float* __restrict__ Wf,
    const float* __restrict__ bf, const float* __restrict__ gam,
    const float* __restrict__ bet, const float* __restrict__ mu,
    const float* __restrict__ var, float* __restrict__ xbuf)
{
    __shared__ float xs[2][FPD];
    const int t = threadIdx.x;
    const int r0 = blockIdx.x * 2;
    for (int i = t; i < 2 * FPD / 4; i += 256)
        ((float4*)xs)[i] = ((const float4*)(fpv + (size_t)r0 * FPD))[i];
    __syncthreads();

    const int j = t & 127, r = t >> 7;
    const float* xr = xs[r];
    float a0 = 0.f, a1 = 0.f, a2 = 0.f, a3 = 0.f;
    for (int k = 0; k < FPD; k += 4) {
        const float4 x4 = *(const float4*)&xr[k];
        a0 = fmaf(x4.x, Wf[(size_t)(k + 0) * FPE + j], a0);
        a1 = fmaf(x4.y, Wf[(size_t)(k + 1) * FPE + j], a1);
        a2 = fmaf(x4.z, Wf[(size_t)(k + 2) * FPE + j], a2);
        a3 = fmaf(x4.w, Wf[(size_t)(k + 3) * FPE + j], a3);
    }
    const float a = (a0 + a1) + (a2 + a3);
    const float sc = rsqrtf(var[j] + BN_EPS) * gam[j];
    const float sh = bet[j] - mu[j] * sc;
    xbuf[(size_t)(r0 + r) * XDIM + 160 + j] = fmaxf(fmaf(a + bf[j], sc, sh), 0.f);
}

// ---------------- K6-K8: row-stationary broadcast FFN ------------------------
// One block per 4 rows; 256 threads own columns (NC cols each). X is read via
// block-uniform pointers -> scalar (SGPR) loads, broadcast into FMA. No LDS,
// no barriers; 8 independent FMA chains per thread.
template<int NC>
__global__ __launch_bounds__(256) void ffn_bcast(
    const float* __restrict__ X, const float* __restrict__ W,
    const float* __restrict__ bias, float* __restrict__ Y,
    int Bv, int Ni, int No, int doRelu)
{
    const int t = threadIdx.x;
    const int r0 = blockIdx.x * 4;
    const float* __restrict__ xp0 = X + (size_t)r0 * Ni;
    const float* __restrict__ xp1 = X + (size_t)min(r0 + 1, Bv - 1) * Ni;
    const float* __restrict__ xp2 = X + (size_t)min(r0 + 2, Bv - 1) * Ni;
    const float* __restrict__ xp3 = X + (size_t)min(r0 + 3, Bv - 1) * Ni;

    float acc0[NC] = {}, acc1[NC] = {}, acc2[NC] = {}, acc3[NC] = {};

    for (int k = 0; k < Ni; k += 8) {
        #pragma unroll
        for (int u = 0; u < 8; ++u) {
            const float x0 = xp0[k + u];
            const float x1 = xp1[k + u];
            const float x2 = xp2[k + u];
            const float x3 = xp3[k + u];
            #pragma unroll
            for (int c = 0; c < NC; ++c) {
                const float w = W[(size_t)(k + u) * No + c * 256 + t];
                acc0[c] = fmaf(x0, w, acc0[c]);
                acc1[c] = fmaf(x1, w, acc1[c]);
                acc2[c] = fmaf(x2, w, acc2[c]);
                acc3[c] = fmaf(x3, w, acc3[c]);
            }
        }
    }

    #pragma unroll
    for (int c = 0; c < NC; ++c) {
        const int col = c * 256 + t;
        const float bv = bias[col];
        float o0 = acc0[c] + bv, o1 = acc1[c] + bv;
        float o2 = acc2[c] + bv, o3 = acc3[c] + bv;
        if (doRelu) {
            o0 = fmaxf(o0, 0.f); o1 = fmaxf(o1, 0.f);
            o2 = fmaxf(o2, 0.f); o3 = fmaxf(o3, 0.f);
        }
        Y[(size_t)r0 * No + col] = o0;
        if (r0 + 1 < Bv) Y[(size_t)(r0 + 1) * No + col] = o1;
        if (r0 + 2 < Bv) Y[(size_t)(r0 + 2) * No + col] = o2;
        if (r0 + 3 < Bv) Y[(size_t)(r0 + 3) * No + col] = o3;
    }
}

extern "C" void kernel_launch(void* const* d_in, const int* in_sizes, int n_in,
                              void* d_out, int out_size, void* d_ws, size_t ws_size,
                              hipStream_t stream)
{
    const float* node_feats = (const float*)d_in[0];
    const float* edge_feats = (const float*)d_in[1];
    const float* fpv        = (const float*)d_in[2];
    const int*   src        = (const int*)d_in[3];
    const int*   dst        = (const int*)d_in[4];
    const int*   gids       = (const int*)d_in[5];
    const float* Wm  = (const float*)d_in[6];
    const float* bm  = (const float*)d_in[7];
    const float* We  = (const float*)d_in[8];
    const float* be  = (const float*)d_in[9];
    const float* Wf  = (const float*)d_in[10];
    const float* bf  = (const float*)d_in[11];
    const float* gam = (const float*)d_in[12];
    const float* bet = (const float*)d_in[13];
    const float* mu  = (const float*)d_in[14];
    const float* var = (const float*)d_in[15];
    const float* W0  = (const float*)d_in[16];
    const float* b0  = (const float*)d_in[17];
    const float* W1  = (const float*)d_in[18];
    const float* b1  = (const float*)d_in[19];
    const float* W2  = (const float*)d_in[20];
    const float* b2  = (const float*)d_in[21];
    const int E = in_sizes[3];

    // workspace layout
    float* xbuf  = (float*)d_ws;                         // [500][288]
    float* h1    = xbuf + (size_t)NB * XDIM;             // [500][512]
    float* h2    = h1 + (size_t)NB * 512;                // [500][512]
    int*   gkey  = (int*)(h2 + (size_t)NB * 512);        // [E]
    int*   ssrc  = gkey + E;                              // [E]
    int*   seid  = ssrc + E;                              // [E]
    int*   histP = seid + E;                              // [NB*HP] padded
    int*   offs  = histP + NB * HP;                       // [NB]
    int*   cursP = offs + NB;                             // [NB*HP] padded

    hipMemsetAsync(histP, 0, NB * HP * sizeof(int), stream);
    hipLaunchKernelGGL(key_hist, dim3(256), dim3(256), 0, stream,
                       dst, gids, gkey, histP, E);
    hipLaunchKernelGGL(scan_kernel, dim3(1), dim3(512), 0, stream,
                       histP, offs, cursP);
    hipLaunchKernelGGL(scatter_kernel, dim3((E + 1023) / 1024), dim3(256), 0, stream,
                       gkey, src, cursP, ssrc, seid, E);
    hipLaunchKernelGGL(graph_accum, dim3(NB), dim3(256), 0, stream,
                       ssrc, seid, node_feats, edge_feats, offs, histP,
                       Wm, bm, We, be, xbuf, E);
    hipLaunchKernelGGL(fp_kernel, dim3(NB / 2), dim3(256), 0, stream,
                       fpv, Wf, bf, gam, bet, mu, var, xbuf);
    hipLaunchKernelGGL((ffn_bcast<2>), dim3((NB + 3) / 4), dim3(256), 0, stream,
                       xbuf, W0, b0, h1, NB, XDIM, 512, 1);
    hipLaunchKernelGGL((ffn_bcast<2>), dim3((NB + 3) / 4), dim3(256), 0, stream,
                       h1, W1, b1, h2, NB, 512, 512, 1);
    hipLaunchKernelGGL((ffn_bcast<1>), dim3((NB + 3) / 4), dim3(256), 0, stream,
                       h2, W2, b2, (float*)d_out, NB, 512, 256, 0);
}